// Round 1
// baseline (645.965 us; speedup 1.0000x reference)
//
#include <hip/hip_runtime.h>
#include <hip/hip_bf16.h>
#include <math.h>

// Problem constants (from reference setup_inputs)
#define B_  64
#define T_  1000
#define D_  512
#define V_  29
#define L_  200
#define S_  401          // 2*L+1
#define VPAD 32          // padded stride for log-prob rows
#define NEGV (-1e9f)
#define BLANK_ 28

// ---------------------------------------------------------------------------
// Kernel 1: fused head (Linear D->V) + log_softmax, writes lp[b][t][v] with
// stride VPAD. One 32-lane group per row (b,t); 8 rows per 256-thread block.
// Rows with t >= feature_lengths[b] are skipped (never read downstream).
// ---------------------------------------------------------------------------
__global__ __launch_bounds__(256) void head_logsoftmax_kernel(
    const float* __restrict__ feat,   // [B][T][D]
    const float* __restrict__ W,      // [D][V]
    const float* __restrict__ bias,   // [V]
    const int*   __restrict__ flen,   // [B]
    float*       __restrict__ lp)     // [B][T][VPAD]
{
    __shared__ float frow[8][D_];
    const int g    = threadIdx.x >> 5;   // row group 0..7
    const int lane = threadIdx.x & 31;
    const int r    = blockIdx.x * 8 + g; // row id 0..63999
    const int b    = r / T_;
    const int t    = r - b * T_;
    const bool active = (t < flen[b]);

    if (active) {
        // stage feature row (512 f32 = 128 float4) into LDS
        const float4* src = (const float4*)(feat + (size_t)r * D_);
        float4* dst = (float4*)frow[g];
        #pragma unroll
        for (int i = 0; i < 4; ++i) dst[lane + 32 * i] = src[lane + 32 * i];
    }
    __syncthreads();

    if (active) {
        float logit = -1e30f;
        if (lane < V_) {
            float a0 = bias[lane], a1 = 0.f, a2 = 0.f, a3 = 0.f;
            const float* w = W + lane;
            #pragma unroll 8
            for (int d = 0; d < D_; d += 4) {
                a0 += frow[g][d]     * w[(size_t)d * V_];
                a1 += frow[g][d + 1] * w[(size_t)(d + 1) * V_];
                a2 += frow[g][d + 2] * w[(size_t)(d + 2) * V_];
                a3 += frow[g][d + 3] * w[(size_t)(d + 3) * V_];
            }
            logit = (a0 + a1) + (a2 + a3);
        }
        // max over the 29 valid lanes (width-32 butterfly)
        float mx = logit;
        #pragma unroll
        for (int off = 16; off; off >>= 1)
            mx = fmaxf(mx, __shfl_xor(mx, off, 32));
        float e = (lane < V_) ? __expf(logit - mx) : 0.f;
        float se = e;
        #pragma unroll
        for (int off = 16; off; off >>= 1)
            se += __shfl_xor(se, off, 32);
        if (lane < V_)
            lp[(size_t)r * VPAD + lane] = logit - mx - __logf(se);
    }
}

// ---------------------------------------------------------------------------
// Kernel 2: CTC alpha recursion. One block per batch sample, 448 threads
// (7 waves) cover S=401 states. Double-buffered LDS alpha, one barrier per
// timestep, 1-step global lp prefetch. Early exit at t == feature_len
// (alpha frozen after that in the reference).
// ---------------------------------------------------------------------------
__global__ __launch_bounds__(448) void ctc_alpha_kernel(
    const float* __restrict__ lp,     // [B][T][VPAD]
    const int*   __restrict__ labels, // [B][L]
    const int*   __restrict__ flen,   // [B]
    const int*   __restrict__ llen,   // [B]
    float*       __restrict__ nll)    // [B]
{
    const int b = blockIdx.x;
    const int s = threadIdx.x;        // state index, active if s < S_
    __shared__ float abuf[2][S_ + 3];

    const float* lpb = lp + (size_t)b * T_ * VPAD;

    // per-thread static trellis data
    int ext = BLANK_;
    int allow = 0;
    if (s < S_ && (s & 1)) {
        int li = (s - 1) >> 1;
        ext = labels[b * L_ + li];
        if (s >= 3) allow = (ext != labels[b * L_ + li - 1]);
        // s == 1: skip transition lands at index -1 -> disallowed
    }
    const int Tb = flen[b];

    // t = 0 init
    if (s < S_) abuf[0][s] = (s < 2) ? lpb[ext] : NEGV;
    __syncthreads();

    float lp_cur = (s < S_) ? lpb[VPAD + ext] : 0.f;   // row t=1 (unused if Tb==1)
    int cur = 0;
    for (int t = 1; t < Tb; ++t) {
        // prefetch next timestep's lp (guarded: only rows < Tb are written)
        float lp_nxt = (s < S_ && (t + 1) < Tb)
                         ? lpb[(size_t)(t + 1) * VPAD + ext] : 0.f;
        if (s < S_) {
            float a0 = abuf[cur][s];
            float a1 = (s >= 1) ? abuf[cur][s - 1] : NEGV;
            float a2 = allow ? abuf[cur][s - 2] : NEGV;
            float m  = fmaxf(fmaxf(a0, a1), a2);
            float sum = __expf(a0 - m) + __expf(a1 - m) + __expf(a2 - m);
            abuf[cur ^ 1][s] = lp_cur + m + __logf(sum);
        }
        __syncthreads();   // writes to buf cur^1 visible; next iter reads it
        cur ^= 1;
        lp_cur = lp_nxt;
    }

    if (s == 0) {
        const int ll = llen[b];
        const int ib = 2 * ll;                      // <= 400
        float l1 = abuf[cur][ib];
        float l2 = (ll > 0) ? abuf[cur][ib > 0 ? ib - 1 : 0] : NEGV;
        float m  = fmaxf(l1, l2);
        float nl = -(m + __logf(__expf(l1 - m) + __expf(l2 - m)));
        // zero_infinity + mean-by-target-length semantics
        nll[b] = (nl < -0.5f * NEGV) ? nl / fmaxf((float)ll, 1.f) : 0.f;
    }
}

// ---------------------------------------------------------------------------
// Kernel 3: mean over B=64 per-sample losses -> scalar
// ---------------------------------------------------------------------------
__global__ __launch_bounds__(64) void reduce_mean_kernel(
    const float* __restrict__ nll, float* __restrict__ out)
{
    float v = nll[threadIdx.x];
    #pragma unroll
    for (int off = 32; off; off >>= 1) v += __shfl_down(v, off);
    if (threadIdx.x == 0) out[0] = v * (1.0f / (float)B_);
}

// ---------------------------------------------------------------------------
extern "C" void kernel_launch(void* const* d_in, const int* in_sizes, int n_in,
                              void* d_out, int out_size, void* d_ws, size_t ws_size,
                              hipStream_t stream) {
    const float* feat   = (const float*)d_in[0];  // [64,1000,512] f32
    const float* W      = (const float*)d_in[1];  // [512,29] f32
    const float* bias   = (const float*)d_in[2];  // [29] f32
    const int*   labels = (const int*)  d_in[3];  // [64,200] i32
    const int*   flen   = (const int*)  d_in[4];  // [64] i32
    const int*   llen   = (const int*)  d_in[5];  // [64] i32
    float* out = (float*)d_out;

    // workspace layout
    float* lp  = (float*)d_ws;                              // B*T*VPAD f32 = 8.192 MB
    float* nll = (float*)((char*)d_ws + (size_t)8 * 1024 * 1024); // B f32

    head_logsoftmax_kernel<<<(B_ * T_) / 8, 256, 0, stream>>>(feat, W, bias, flen, lp);
    ctc_alpha_kernel<<<B_, 448, 0, stream>>>(lp, labels, flen, llen, nll);
    reduce_mean_kernel<<<1, 64, 0, stream>>>(nll, out);
}